// Round 9
// baseline (333.483 us; speedup 1.0000x reference)
//
#include <hip/hip_runtime.h>
#include <stdint.h>

#define HEADS 12
#define HD 32
#define DIM 384
#define NQKV 1152
#define NPIX 4096
#define NB 16

typedef __attribute__((ext_vector_type(8))) short bf16x8;
typedef __attribute__((ext_vector_type(4))) float f32x4;

__device__ __forceinline__ unsigned short f2bf(float f) {
  uint32_t u = __builtin_bit_cast(uint32_t, f);
  u += 0x7FFF + ((u >> 16) & 1);
  return (unsigned short)(u >> 16);
}

__device__ __forceinline__ uint32_t cvtpk(float lo, float hi) {
  uint32_t r;
  asm("v_cvt_pk_bf16_f32 %0, %1, %2" : "=v"(r) : "v"(lo), "v"(hi));
  return r;
}

#define GL_LDS(gp, lp) __builtin_amdgcn_global_load_lds( \
    (const __attribute__((address_space(1))) void*)(gp),  \
    (__attribute__((address_space(3))) void*)(lp), 16, 0, 0)

#define MFMA32 __builtin_amdgcn_mfma_f32_16x16x32_bf16

// ---------------------------------------------------------------- converts
// blocks [0,1728): weight transposes; [1728,1792): bias+mask table [4][64][64].
__global__ void convert_w(const float* __restrict__ wqkv,
                          const float* __restrict__ wout,
                          const float* __restrict__ pos,
                          unsigned short* __restrict__ wqkvT,
                          unsigned short* __restrict__ woutT,
                          float* __restrict__ tab) {
  int bid = blockIdx.x;
  if (bid < 1728) {
    int tid = bid * 256 + threadIdx.x;
    if (tid < NQKV * DIM) {                   // wqkvT[n][k] = wqkv[k][n]
      int n = tid / DIM, k = tid % DIM;
      wqkvT[tid] = f2bf(wqkv[(size_t)k * NQKV + n]);
    }
    if (tid < DIM * DIM) {                    // woutT[n][k] = wout[k][n]
      int n = tid / DIM, k = tid % DIM;
      woutT[tid] = f2bf(wout[(size_t)k * DIM + n]);
    }
  } else {
    int tid = (bid - 1728) * 256 + threadIdx.x;  // 0..16383
    int v = tid >> 12, rem = tid & 4095;
    int i = rem >> 6, j = rem & 63;
    int xi = i >> 3, yi = i & 7, xj = j >> 3, yj = j & 7;
    float val = pos[(xj - xi + 7) * 15 + (yj - yi + 7)];
    if ((v & 1) && ((i >= 32) != (j >= 32))) val = -1e30f;
    if ((v & 2) && ((yi >= 4) != (yj >= 4))) val = -1e30f;
    tab[tid] = val;
  }
}

// ---------------------------------------------------------------- GEMM1: qkv = x(f32) @ wqkvT^T
// m97 structure with write-side fused convert: A staged via registers
// (float4 loads -> v_cvt_pk -> ds_write_b128, convert runs ONCE per element),
// B via 16B global_load_lds. LDS stays 32KB bf16 (4 blocks/CU). Read side
// identical to the verified R4 kernel (XOR key = row&7, applied at the
// ds_write address). XCD-chunked grid.
__global__ __launch_bounds__(256, 4) void gemm_qkv(
    const float* __restrict__ x,             // [65536][384] f32
    const unsigned short* __restrict__ wT,   // [1152][384] bf16
    unsigned short* __restrict__ qkv)        // [65536][1152] bf16
{
  __shared__ unsigned short lA[128 * 64];    // 16 KB
  __shared__ unsigned short lB[128 * 64];    // 16 KB
  const int tid = threadIdx.x;
  const int wid = tid >> 6, lane = tid & 63;
  const int wr = wid >> 1, wc = wid & 1;
  const int lr = lane >> 4, lc = lane & 15;

  // XCD swizzle: 4608 blocks = 8 xcd * (64 mt * 9 nt)
  const int f = blockIdx.x;
  const int xcd = f & 7, idx = f >> 3;
  const int nt = idx % 9, mt = xcd * 64 + idx / 9;
  const int m0 = mt * 128, n0 = nt * 128;

  // A reg-staging: thread handles row ar = tid>>1, granules ag..ag+3 (8 bf16 each)
  const int ar = tid >> 1;
  const int ag = (tid & 1) * 4;
  const float* axp = x + (size_t)(m0 + ar) * DIM + ag * 8;
  unsigned short* awp = &lA[ar * 64];
  const int akey = ar & 7;

  // B staging via global_load_lds: key = row&7, pre-swizzled source col.
  const int sBrow = wid * 32 + (lane >> 3);
  const int sBcol = ((lane & 7) ^ (lane >> 3)) * 8;
  const unsigned short* bgp = wT + (size_t)(n0 + sBrow) * DIM + sBcol;

  const f32x4 z4 = {0.f, 0.f, 0.f, 0.f};
  f32x4 acc[4][4];
#pragma unroll
  for (int i = 0; i < 4; i++)
#pragma unroll
    for (int j = 0; j < 4; j++) acc[i][j] = z4;

  auto stage = [&](int t) {
    // B: async direct-to-LDS (issue first so it overlaps the A reg path)
#pragma unroll
    for (int i = 0; i < 4; i++)
      GL_LDS(bgp + (size_t)(i * 8) * DIM + t * 64, &lB[(wid * 4 + i) * 512]);
    // A: f32 -> bf16 convert on the write side (once per element)
#pragma unroll
    for (int q = 0; q < 4; ++q) {
      float4 f0 = *(const float4*)(axp + t * 64 + q * 8);
      float4 f1 = *(const float4*)(axp + t * 64 + q * 8 + 4);
      union { uint32_t u[4]; bf16x8 v; } up;
      up.u[0] = cvtpk(f0.x, f0.y);
      up.u[1] = cvtpk(f0.z, f0.w);
      up.u[2] = cvtpk(f1.x, f1.y);
      up.u[3] = cvtpk(f1.z, f1.w);
      *(bf16x8*)&awp[((ag + q) ^ akey) * 8] = up.v;
    }
  };
  auto compute = [&]() {
    const int sw = lc & 7;
#pragma unroll
    for (int kk = 0; kk < 2; kk++) {
      bf16x8 afr[4], bfr[4];
#pragma unroll
      for (int mi = 0; mi < 4; mi++)
        afr[mi] = *(const bf16x8*)&lA[(wr * 64 + mi * 16 + lc) * 64 + (((kk * 4 + lr) ^ sw) * 8)];
#pragma unroll
      for (int ni = 0; ni < 4; ni++)
        bfr[ni] = *(const bf16x8*)&lB[(wc * 64 + ni * 16 + lc) * 64 + (((kk * 4 + lr) ^ sw) * 8)];
#pragma unroll
      for (int mi = 0; mi < 4; mi++)
#pragma unroll
        for (int ni = 0; ni < 4; ni++)
          acc[mi][ni] = MFMA32(afr[mi], bfr[ni], acc[mi][ni], 0, 0, 0);
    }
  };

  for (int t = 0; t < 6; ++t) {
    stage(t);
    __syncthreads();
    compute();
    if (t < 5) __syncthreads();
  }

#pragma unroll
  for (int mi = 0; mi < 4; mi++) {
    int row = m0 + wr * 64 + mi * 16 + lr * 4;
#pragma unroll
    for (int reg = 0; reg < 4; reg++) {
      size_t rb = (size_t)(row + reg) * NQKV + n0 + wc * 64 + lc;
#pragma unroll
      for (int ni = 0; ni < 4; ni++)
        qkv[rb + ni * 16] = f2bf(acc[mi][ni][reg]);
    }
  }
}

// ---------------------------------------------------------------- attention (R4 verbatim)
// one wave per (b, head, window); swapped QK^T (S^T in regs), in-register
// softmax + normalize, cvt_pk+ds_bpermute P redistribution (no P LDS),
// XOR-swizzled wave-private V^T LDS, no __syncthreads.
__global__ __launch_bounds__(256) void attn_kernel(
    const unsigned short* __restrict__ qkv,  // [65536][1152] bf16
    const float* __restrict__ tab,           // [4][64][64] bias+mask
    unsigned short* __restrict__ Z)          // [65536][384] bf16
{
  __shared__ unsigned short Vt[4][32 * 80];

  const int wid = threadIdx.x >> 6, lane = threadIdx.x & 63;
  const int lr = lane >> 4, lc = lane & 15;
  const int task = blockIdx.x * 4 + wid;          // 12288 tasks
  const int win = task & 63;
  const int head = (task >> 6) % HEADS;
  const int b = task / (HEADS * 64);
  const int wh = win >> 3, ww = win & 7;
  const float* tv = tab + (((wh == 7) ? 1 : 0) + ((ww == 7) ? 2 : 0)) * 4096;

  auto pixof = [&](int t) {
    int hh = (wh * 8 + (t >> 3) + 4) & 63;
    int w2 = (ww * 8 + (t & 7) + 4) & 63;
    return hh * 64 + w2;
  };

  unsigned short* vt = &Vt[wid][0];
  bf16x8 qf[4], kf[4];
#pragma unroll
  for (int g = 0; g < 4; ++g) {
    int t = g * 16 + lc;
    const unsigned short* base =
        qkv + (size_t)(b * NPIX + pixof(t)) * NQKV + head * HD + lr * 8;
    qf[g] = *(const bf16x8*)(base);
    kf[g] = *(const bf16x8*)(base + DIM);
    union { bf16x8 v; unsigned short s[8]; } uv;
    uv.v = *(const bf16x8*)(base + 2 * DIM);
    // Vt[d][t] = V[t][d], col-block XOR-swizzled by (d>>2)&3
#pragma unroll
    for (int j = 0; j < 8; j++) {
      int row = lr * 8 + j;
      int addr = row * 80 + (((g * 2 + (lc >> 3)) ^ ((row >> 2) & 3)) << 3) + (lc & 7);
      vt[addr] = uv.s[j];
    }
  }

  const float SC = 0.17677669529663687f;   // 32^-0.5
  const f32x4 z4 = {0.f, 0.f, 0.f, 0.f};
  uint32_t pf[4][2][4];                    // [i-tile][kslot][u32 pair]
  const int srcA = (lc + 16 * (2 * (lr & 1))) << 2;   // lane byte-addr, lr'=2(lr&1)
  const int srcB = srcA + 64;                         // lr'=2(lr&1)+1
  const bool hiSel = (lr >> 1) != 0;

#pragma unroll
  for (int bq = 0; bq < 4; bq++) {
    // bias tile: T[i = bq*16+lc][j = 16a+4lr+reg], contiguous 4 j's
    f32x4 tb[4];
#pragma unroll
    for (int a = 0; a < 4; a++)
      tb[a] = *(const f32x4*)&tv[(bq * 16 + lc) * 64 + a * 16 + lr * 4];
    // swapped QK^T: s[a][reg] = S^T[j = 16a+4lr+reg][i = bq*16+lc]
    f32x4 s[4];
#pragma unroll
    for (int a = 0; a < 4; a++)
      s[a] = MFMA32(kf[a], qf[bq], z4, 0, 0, 0);

    float m = -3.0e38f;
#pragma unroll
    for (int a = 0; a < 4; a++)
#pragma unroll
      for (int r = 0; r < 4; r++) {
        float val = s[a][r] * SC + tb[a][r];
        s[a][r] = val;
        m = fmaxf(m, val);
      }
    m = fmaxf(m, __shfl_xor(m, 16));
    m = fmaxf(m, __shfl_xor(m, 32));
    float sum = 0.f;
#pragma unroll
    for (int a = 0; a < 4; a++)
#pragma unroll
      for (int r = 0; r < 4; r++) {
        float p = exp2f((s[a][r] - m) * 1.44269504f);
        s[a][r] = p;
        sum += p;
      }
    sum += __shfl_xor(sum, 16);
    sum += __shfl_xor(sum, 32);
    float iv = 1.0f / sum;

    // pack normalized P to bf16 pairs: pk[a][w] = (reg 2w, reg 2w+1)
    uint32_t pk[4][2];
#pragma unroll
    for (int a = 0; a < 4; a++)
#pragma unroll
      for (int w = 0; w < 2; w++)
        pk[a][w] = cvtpk(s[a][2 * w] * iv, s[a][2 * w + 1] * iv);
    // redistribute: pf[bq][kk] elem-pair wp holds j = 32kk+8lr+2wp,+1
    // source: lane lr' = 2(lr&1)+(wp>>1), slot pk[2kk + (lr>>1)][wp&1]
#pragma unroll
    for (int kk = 0; kk < 2; kk++)
#pragma unroll
      for (int wp = 0; wp < 4; wp++) {
        int sa = (wp >> 1) ? srcB : srcA;
        uint32_t lo = (uint32_t)__builtin_amdgcn_ds_bpermute(sa, (int)pk[2 * kk][wp & 1]);
        uint32_t hi = (uint32_t)__builtin_amdgcn_ds_bpermute(sa, (int)pk[2 * kk + 1][wp & 1]);
        pf[bq][kk][wp] = hiSel ? hi : lo;
      }
  }

  asm volatile("s_waitcnt lgkmcnt(0)" ::: "memory");

  f32x4 oacc[4][2];
#pragma unroll
  for (int i = 0; i < 4; i++) { oacc[i][0] = z4; oacc[i][1] = z4; }

#pragma unroll
  for (int kk = 0; kk < 2; kk++) {
    bf16x8 vfr[2];
#pragma unroll
    for (int dt = 0; dt < 2; dt++) {
      int rowd = dt * 16 + lc;
      int addr = rowd * 80 + ((((kk * 4 + lr) ^ (lc >> 2)) & 7) << 3);
      vfr[dt] = *(const bf16x8*)&vt[addr];
    }
#pragma unroll
    for (int mi = 0; mi < 4; mi++) {
      union { uint32_t u[4]; bf16x8 v; } pu;
      pu.u[0] = pf[mi][kk][0]; pu.u[1] = pf[mi][kk][1];
      pu.u[2] = pf[mi][kk][2]; pu.u[3] = pf[mi][kk][3];
#pragma unroll
      for (int dt = 0; dt < 2; dt++)
        oacc[mi][dt] = MFMA32(pu.v, vfr[dt], oacc[mi][dt], 0, 0, 0);
    }
  }

#pragma unroll
  for (int mi = 0; mi < 4; mi++) {
#pragma unroll
    for (int reg = 0; reg < 4; reg++) {
      int i = mi * 16 + lr * 4 + reg;
      size_t zb = ((size_t)b * NPIX + pixof(i)) * DIM + head * HD;
#pragma unroll
      for (int dt = 0; dt < 2; dt++)
        Z[zb + dt * 16 + lc] = f2bf(oacc[mi][dt][reg]);
    }
  }
}

// ---------------------------------------------------------------- GEMM2: out = Z @ woutT^T + b
// m97 single-buffer structure + XCD swizzle. M=65536, N=384, K=384.
__global__ __launch_bounds__(256, 4) void gemm_out(
    const unsigned short* __restrict__ Zb,   // [65536][384]
    const unsigned short* __restrict__ wT,   // [384][384]
    const float* __restrict__ bout,
    float* __restrict__ out)                 // [65536][384]
{
  __shared__ unsigned short lA[128 * 64];
  __shared__ unsigned short lB[128 * 64];
  const int tid = threadIdx.x;
  const int wid = tid >> 6, lane = tid & 63;
  const int wr = wid >> 1, wc = wid & 1;
  const int lr = lane >> 4, lc = lane & 15;

  // XCD swizzle: 1536 blocks = 8 xcd * (64 mt * 3 nt)
  const int f = blockIdx.x;
  const int xcd = f & 7, idx = f >> 3;
  const int nt = idx % 3, mt = xcd * 64 + idx / 3;
  const int m0 = mt * 128, n0 = nt * 128;

  const int srow = wid * 32 + (lane >> 3);
  const int scol = ((lane & 7) ^ (lane >> 3)) * 8;
  const unsigned short* agp = Zb + (size_t)(m0 + srow) * DIM + scol;
  const unsigned short* bgp = wT + (size_t)(n0 + srow) * DIM + scol;

  const f32x4 z4 = {0.f, 0.f, 0.f, 0.f};
  f32x4 acc[4][4];
#pragma unroll
  for (int i = 0; i < 4; i++)
#pragma unroll
    for (int j = 0; j < 4; j++) acc[i][j] = z4;

  auto stage = [&](int t) {
#pragma unroll
    for (int i = 0; i < 4; i++) {
      GL_LDS(agp + (size_t)(i * 8) * DIM + t * 64, &lA[(wid * 4 + i) * 512]);
      GL_LDS(bgp + (size_t)(i * 8) * DIM + t * 64, &lB[(wid * 4 + i) * 512]);
    }
  };
  auto compute = [&]() {
    const int sw = lc & 7;
#pragma unroll
    for (int kk = 0; kk < 2; kk++) {
      bf16x8 afr[4], bfr[4];
#pragma unroll
      for (int mi = 0; mi < 4; mi++)
        afr[mi] = *(const bf16x8*)&lA[(wr * 64 + mi * 16 + lc) * 64 + (((kk * 4 + lr) ^ sw) * 8)];
#pragma unroll
      for (int ni = 0; ni < 4; ni++)
        bfr[ni] = *(const bf16x8*)&lB[(wc * 64 + ni * 16 + lc) * 64 + (((kk * 4 + lr) ^ sw) * 8)];
#pragma unroll
      for (int mi = 0; mi < 4; mi++)
#pragma unroll
        for (int ni = 0; ni < 4; ni++)
          acc[mi][ni] = MFMA32(afr[mi], bfr[ni], acc[mi][ni], 0, 0, 0);
    }
  };

  for (int t = 0; t < 6; ++t) {
    stage(t);
    __syncthreads();
    compute();
    if (t < 5) __syncthreads();
  }

  float bo[4];
#pragma unroll
  for (int ni = 0; ni < 4; ni++) bo[ni] = bout[n0 + wc * 64 + ni * 16 + lc];

#pragma unroll
  for (int mi = 0; mi < 4; mi++) {
    int row = m0 + wr * 64 + mi * 16 + lr * 4;
#pragma unroll
    for (int reg = 0; reg < 4; reg++) {
      size_t rb = (size_t)(row + reg) * DIM + n0 + wc * 64 + lc;
#pragma unroll
      for (int ni = 0; ni < 4; ni++)
        out[rb + ni * 16] = acc[mi][ni][reg] + bo[ni];
    }
  }
}

// ---------------------------------------------------------------- launch
extern "C" void kernel_launch(void* const* d_in, const int* in_sizes, int n_in,
                              void* d_out, int out_size, void* d_ws, size_t ws_size,
                              hipStream_t stream) {
  const float* x    = (const float*)d_in[0];
  const float* wqkv = (const float*)d_in[1];
  const float* pos  = (const float*)d_in[2];
  const float* wout = (const float*)d_in[3];
  const float* bout = (const float*)d_in[4];
  float* out = (float*)d_out;

  char* ws = (char*)d_ws;
  unsigned short* wqkvT = (unsigned short*)ws;                          // 1152*384*2 = 884736
  unsigned short* woutT = (unsigned short*)(ws + 884736);               // 384*384*2  = 294912
  unsigned short* qkv   = (unsigned short*)(ws + 1179648);              // 65536*1152*2 = 150994944
  unsigned short* Zb    = (unsigned short*)(ws + 1179648 + 150994944);  // 65536*384*2
  float* tab = out;   // d_out as scratch for 64KB bias table (overwritten by gemm_out)

  convert_w<<<1792, 256, 0, stream>>>(wqkv, wout, pos, wqkvT, woutT, tab);
  gemm_qkv<<<4608, 256, 0, stream>>>(x, wqkvT, qkv);
  attn_kernel<<<3072, 256, 0, stream>>>(qkv, tab, Zb);
  gemm_out<<<1536, 256, 0, stream>>>(Zb, woutT, bout, out);
}

// Round 10
// 184.742 us; speedup vs baseline: 1.8051x; 1.8051x over previous
//
#include <hip/hip_runtime.h>
#include <stdint.h>

#define HEADS 12
#define HD 32
#define DIM 384
#define NQKV 1152
#define NPIX 4096
#define NB 16

typedef __attribute__((ext_vector_type(8))) short bf16x8;
typedef __attribute__((ext_vector_type(4))) float f32x4;

__device__ __forceinline__ unsigned short f2bf(float f) {
  uint32_t u = __builtin_bit_cast(uint32_t, f);
  u += 0x7FFF + ((u >> 16) & 1);
  return (unsigned short)(u >> 16);
}

__device__ __forceinline__ uint32_t cvtpk(float lo, float hi) {
  uint32_t r;
  asm("v_cvt_pk_bf16_f32 %0, %1, %2" : "=v"(r) : "v"(lo), "v"(hi));
  return r;
}

#define GL_LDS(gp, lp) __builtin_amdgcn_global_load_lds( \
    (const __attribute__((address_space(1))) void*)(gp),  \
    (__attribute__((address_space(3))) void*)(lp), 16, 0, 0)

#define MFMA32 __builtin_amdgcn_mfma_f32_16x16x32_bf16

// ---------------------------------------------------------------- converts
// blocks [0,12288): x f32 -> bf16; [12288,14016): weight transposes;
// [14016,14080): bias+mask table [4][64][64] f32 (written to d_out scratch).
__global__ void convert_all(const float* __restrict__ x,
                            const float* __restrict__ wqkv,
                            const float* __restrict__ wout,
                            const float* __restrict__ pos,
                            unsigned short* __restrict__ xb,
                            unsigned short* __restrict__ wqkvT,
                            unsigned short* __restrict__ woutT,
                            float* __restrict__ tab) {
  int bid = blockIdx.x;
  if (bid < 12288) {
    int i = bid * 256 + threadIdx.x;          // 3145728 threads x 8 elems
    const float4* xp = (const float4*)x;
    float4 a = xp[2 * i], b2 = xp[2 * i + 1];
    union { bf16x8 v; unsigned short s[8]; } u;
    u.s[0] = f2bf(a.x);  u.s[1] = f2bf(a.y);
    u.s[2] = f2bf(a.z);  u.s[3] = f2bf(a.w);
    u.s[4] = f2bf(b2.x); u.s[5] = f2bf(b2.y);
    u.s[6] = f2bf(b2.z); u.s[7] = f2bf(b2.w);
    ((bf16x8*)xb)[i] = u.v;
  } else if (bid < 14016) {
    int tid = (bid - 12288) * 256 + threadIdx.x;
    if (tid < NQKV * DIM) {                   // wqkvT[n][k] = wqkv[k][n]
      int n = tid / DIM, k = tid % DIM;
      wqkvT[tid] = f2bf(wqkv[(size_t)k * NQKV + n]);
    }
    if (tid < DIM * DIM) {                    // woutT[n][k] = wout[k][n]
      int n = tid / DIM, k = tid % DIM;
      woutT[tid] = f2bf(wout[(size_t)k * DIM + n]);
    }
  } else {
    int tid = (bid - 14016) * 256 + threadIdx.x;  // 0..16383
    int v = tid >> 12, rem = tid & 4095;
    int i = rem >> 6, j = rem & 63;
    int xi = i >> 3, yi = i & 7, xj = j >> 3, yj = j & 7;
    float val = pos[(xj - xi + 7) * 15 + (yj - yi + 7)];
    if ((v & 1) && ((i >= 32) != (j >= 32))) val = -1e30f;
    if ((v & 2) && ((yi >= 4) != (yj >= 4))) val = -1e30f;
    tab[tid] = val;
  }
}

// ---------------------------------------------------------------- GEMM1: qkv = xb @ wqkvT^T
// m97-style single-buffer, BM=256 tile: A [256][64] bf16 (32KB) + B [128][64]
// (16KB), both via 16B global_load_lds with XOR-swizzled source col. Each of
// 4 waves owns 64 rows x 128 cols (acc[4][8], 64 MFMA per K-step vs 24
// ds_reads — 4x the matrix work per barrier pair of the 128^2 tile).
// XCD-chunked grid.
__global__ __launch_bounds__(256, 2) void gemm_qkv(
    const unsigned short* __restrict__ xb,   // [65536][384]
    const unsigned short* __restrict__ wT,   // [1152][384]
    unsigned short* __restrict__ qkv)        // [65536][1152]
{
  __shared__ unsigned short lA[256 * 64];    // 32 KB
  __shared__ unsigned short lB[128 * 64];    // 16 KB
  const int tid = threadIdx.x;
  const int wid = tid >> 6, lane = tid & 63;
  const int lr = lane >> 4, lc = lane & 15;

  // XCD swizzle: 2304 blocks = 8 xcd * (32 mt * 9 nt)
  const int f = blockIdx.x;
  const int xcd = f & 7, idx = f >> 3;
  const int nt = idx % 9, mt = xcd * 32 + idx / 9;
  const int m0 = mt * 256, n0 = nt * 128;

  const int srow = lane >> 3;                              // 0..7 (== row&7)
  const int scol = ((lane & 7) ^ srow) * 8;                // pre-swizzled src col
  const unsigned short* agp = xb + (size_t)(m0 + wid * 64 + srow) * DIM + scol;
  const unsigned short* bgp = wT + (size_t)(n0 + wid * 32 + srow) * DIM + scol;

  const f32x4 z4 = {0.f, 0.f, 0.f, 0.f};
  f32x4 acc[4][8];
#pragma unroll
  for (int i = 0; i < 4; i++)
#pragma unroll
    for (int j = 0; j < 8; j++) acc[i][j] = z4;

  auto stage = [&](int t) {
#pragma unroll
    for (int i = 0; i < 8; i++)
      GL_LDS(agp + (size_t)(i * 8) * DIM + t * 64, &lA[(wid * 64 + i * 8) * 64]);
#pragma unroll
    for (int i = 0; i < 4; i++)
      GL_LDS(bgp + (size_t)(i * 8) * DIM + t * 64, &lB[(wid * 32 + i * 8) * 64]);
  };
  auto compute = [&]() {
    const int sw = lc & 7;
#pragma unroll
    for (int kk = 0; kk < 2; kk++) {
      bf16x8 afr[4], bfr[8];
#pragma unroll
      for (int mi = 0; mi < 4; mi++)
        afr[mi] = *(const bf16x8*)&lA[(wid * 64 + mi * 16 + lc) * 64 + (((kk * 4 + lr) ^ sw) * 8)];
#pragma unroll
      for (int ni = 0; ni < 8; ni++)
        bfr[ni] = *(const bf16x8*)&lB[(ni * 16 + lc) * 64 + (((kk * 4 + lr) ^ sw) * 8)];
#pragma unroll
      for (int mi = 0; mi < 4; mi++)
#pragma unroll
        for (int ni = 0; ni < 8; ni++)
          acc[mi][ni] = MFMA32(afr[mi], bfr[ni], acc[mi][ni], 0, 0, 0);
    }
  };

  for (int t = 0; t < 6; ++t) {
    stage(t);
    __syncthreads();
    compute();
    if (t < 5) __syncthreads();
  }

#pragma unroll
  for (int mi = 0; mi < 4; mi++) {
    int row = m0 + wid * 64 + mi * 16 + lr * 4;
#pragma unroll
    for (int reg = 0; reg < 4; reg++) {
      size_t rb = (size_t)(row + reg) * NQKV + n0 + lc;
#pragma unroll
      for (int ni = 0; ni < 8; ni++)
        qkv[rb + ni * 16] = f2bf(acc[mi][ni][reg]);
    }
  }
}

// ---------------------------------------------------------------- attention (R4 verbatim)
// one wave per (b, head, window); swapped QK^T (S^T in regs), in-register
// softmax + normalize, cvt_pk+ds_bpermute P redistribution (no P LDS),
// XOR-swizzled wave-private V^T LDS, no __syncthreads.
__global__ __launch_bounds__(256) void attn_kernel(
    const unsigned short* __restrict__ qkv,  // [65536][1152] bf16
    const float* __restrict__ tab,           // [4][64][64] bias+mask
    unsigned short* __restrict__ Z)          // [65536][384] bf16
{
  __shared__ unsigned short Vt[4][32 * 80];

  const int wid = threadIdx.x >> 6, lane = threadIdx.x & 63;
  const int lr = lane >> 4, lc = lane & 15;
  const int task = blockIdx.x * 4 + wid;          // 12288 tasks
  const int win = task & 63;
  const int head = (task >> 6) % HEADS;
  const int b = task / (HEADS * 64);
  const int wh = win >> 3, ww = win & 7;
  const float* tv = tab + (((wh == 7) ? 1 : 0) + ((ww == 7) ? 2 : 0)) * 4096;

  auto pixof = [&](int t) {
    int hh = (wh * 8 + (t >> 3) + 4) & 63;
    int w2 = (ww * 8 + (t & 7) + 4) & 63;
    return hh * 64 + w2;
  };

  unsigned short* vt = &Vt[wid][0];
  bf16x8 qf[4], kf[4];
#pragma unroll
  for (int g = 0; g < 4; ++g) {
    int t = g * 16 + lc;
    const unsigned short* base =
        qkv + (size_t)(b * NPIX + pixof(t)) * NQKV + head * HD + lr * 8;
    qf[g] = *(const bf16x8*)(base);
    kf[g] = *(const bf16x8*)(base + DIM);
    union { bf16x8 v; unsigned short s[8]; } uv;
    uv.v = *(const bf16x8*)(base + 2 * DIM);
    // Vt[d][t] = V[t][d], col-block XOR-swizzled by (d>>2)&3
#pragma unroll
    for (int j = 0; j < 8; j++) {
      int row = lr * 8 + j;
      int addr = row * 80 + (((g * 2 + (lc >> 3)) ^ ((row >> 2) & 3)) << 3) + (lc & 7);
      vt[addr] = uv.s[j];
    }
  }

  const float SC = 0.17677669529663687f;   // 32^-0.5
  const f32x4 z4 = {0.f, 0.f, 0.f, 0.f};
  uint32_t pf[4][2][4];                    // [i-tile][kslot][u32 pair]
  const int srcA = (lc + 16 * (2 * (lr & 1))) << 2;   // lane byte-addr, lr'=2(lr&1)
  const int srcB = srcA + 64;                         // lr'=2(lr&1)+1
  const bool hiSel = (lr >> 1) != 0;

#pragma unroll
  for (int bq = 0; bq < 4; bq++) {
    // bias tile: T[i = bq*16+lc][j = 16a+4lr+reg], contiguous 4 j's
    f32x4 tb[4];
#pragma unroll
    for (int a = 0; a < 4; a++)
      tb[a] = *(const f32x4*)&tv[(bq * 16 + lc) * 64 + a * 16 + lr * 4];
    // swapped QK^T: s[a][reg] = S^T[j = 16a+4lr+reg][i = bq*16+lc]
    f32x4 s[4];
#pragma unroll
    for (int a = 0; a < 4; a++)
      s[a] = MFMA32(kf[a], qf[bq], z4, 0, 0, 0);

    float m = -3.0e38f;
#pragma unroll
    for (int a = 0; a < 4; a++)
#pragma unroll
      for (int r = 0; r < 4; r++) {
        float val = s[a][r] * SC + tb[a][r];
        s[a][r] = val;
        m = fmaxf(m, val);
      }
    m = fmaxf(m, __shfl_xor(m, 16));
    m = fmaxf(m, __shfl_xor(m, 32));
    float sum = 0.f;
#pragma unroll
    for (int a = 0; a < 4; a++)
#pragma unroll
      for (int r = 0; r < 4; r++) {
        float p = exp2f((s[a][r] - m) * 1.44269504f);
        s[a][r] = p;
        sum += p;
      }
    sum += __shfl_xor(sum, 16);
    sum += __shfl_xor(sum, 32);
    float iv = 1.0f / sum;

    // pack normalized P to bf16 pairs: pk[a][w] = (reg 2w, reg 2w+1)
    uint32_t pk[4][2];
#pragma unroll
    for (int a = 0; a < 4; a++)
#pragma unroll
      for (int w = 0; w < 2; w++)
        pk[a][w] = cvtpk(s[a][2 * w] * iv, s[a][2 * w + 1] * iv);
    // redistribute: pf[bq][kk] elem-pair wp holds j = 32kk+8lr+2wp,+1
    // source: lane lr' = 2(lr&1)+(wp>>1), slot pk[2kk + (lr>>1)][wp&1]
#pragma unroll
    for (int kk = 0; kk < 2; kk++)
#pragma unroll
      for (int wp = 0; wp < 4; wp++) {
        int sa = (wp >> 1) ? srcB : srcA;
        uint32_t lo = (uint32_t)__builtin_amdgcn_ds_bpermute(sa, (int)pk[2 * kk][wp & 1]);
        uint32_t hi = (uint32_t)__builtin_amdgcn_ds_bpermute(sa, (int)pk[2 * kk + 1][wp & 1]);
        pf[bq][kk][wp] = hiSel ? hi : lo;
      }
  }

  asm volatile("s_waitcnt lgkmcnt(0)" ::: "memory");

  f32x4 oacc[4][2];
#pragma unroll
  for (int i = 0; i < 4; i++) { oacc[i][0] = z4; oacc[i][1] = z4; }

#pragma unroll
  for (int kk = 0; kk < 2; kk++) {
    bf16x8 vfr[2];
#pragma unroll
    for (int dt = 0; dt < 2; dt++) {
      int rowd = dt * 16 + lc;
      int addr = rowd * 80 + ((((kk * 4 + lr) ^ (lc >> 2)) & 7) << 3);
      vfr[dt] = *(const bf16x8*)&vt[addr];
    }
#pragma unroll
    for (int mi = 0; mi < 4; mi++) {
      union { uint32_t u[4]; bf16x8 v; } pu;
      pu.u[0] = pf[mi][kk][0]; pu.u[1] = pf[mi][kk][1];
      pu.u[2] = pf[mi][kk][2]; pu.u[3] = pf[mi][kk][3];
#pragma unroll
      for (int dt = 0; dt < 2; dt++)
        oacc[mi][dt] = MFMA32(pu.v, vfr[dt], oacc[mi][dt], 0, 0, 0);
    }
  }

#pragma unroll
  for (int mi = 0; mi < 4; mi++) {
#pragma unroll
    for (int reg = 0; reg < 4; reg++) {
      int i = mi * 16 + lr * 4 + reg;
      size_t zb = ((size_t)b * NPIX + pixof(i)) * DIM + head * HD;
#pragma unroll
      for (int dt = 0; dt < 2; dt++)
        Z[zb + dt * 16 + lc] = f2bf(oacc[mi][dt][reg]);
    }
  }
}

// ---------------------------------------------------------------- GEMM2: out = Z @ woutT^T + b
// m97 single-buffer structure + XCD swizzle. M=65536, N=384, K=384.
__global__ __launch_bounds__(256, 4) void gemm_out(
    const unsigned short* __restrict__ Zb,   // [65536][384]
    const unsigned short* __restrict__ wT,   // [384][384]
    const float* __restrict__ bout,
    float* __restrict__ out)                 // [65536][384]
{
  __shared__ unsigned short lA[128 * 64];
  __shared__ unsigned short lB[128 * 64];
  const int tid = threadIdx.x;
  const int wid = tid >> 6, lane = tid & 63;
  const int wr = wid >> 1, wc = wid & 1;
  const int lr = lane >> 4, lc = lane & 15;

  // XCD swizzle: 1536 blocks = 8 xcd * (64 mt * 3 nt)
  const int f = blockIdx.x;
  const int xcd = f & 7, idx = f >> 3;
  const int nt = idx % 3, mt = xcd * 64 + idx / 3;
  const int m0 = mt * 128, n0 = nt * 128;

  const int srow = wid * 32 + (lane >> 3);
  const int scol = ((lane & 7) ^ (lane >> 3)) * 8;
  const unsigned short* agp = Zb + (size_t)(m0 + srow) * DIM + scol;
  const unsigned short* bgp = wT + (size_t)(n0 + srow) * DIM + scol;

  const f32x4 z4 = {0.f, 0.f, 0.f, 0.f};
  f32x4 acc[4][4];
#pragma unroll
  for (int i = 0; i < 4; i++)
#pragma unroll
    for (int j = 0; j < 4; j++) acc[i][j] = z4;

  auto stage = [&](int t) {
#pragma unroll
    for (int i = 0; i < 4; i++) {
      GL_LDS(agp + (size_t)(i * 8) * DIM + t * 64, &lA[(wid * 4 + i) * 512]);
      GL_LDS(bgp + (size_t)(i * 8) * DIM + t * 64, &lB[(wid * 4 + i) * 512]);
    }
  };
  auto compute = [&]() {
    const int sw = lc & 7;
#pragma unroll
    for (int kk = 0; kk < 2; kk++) {
      bf16x8 afr[4], bfr[4];
#pragma unroll
      for (int mi = 0; mi < 4; mi++)
        afr[mi] = *(const bf16x8*)&lA[(wr * 64 + mi * 16 + lc) * 64 + (((kk * 4 + lr) ^ sw) * 8)];
#pragma unroll
      for (int ni = 0; ni < 4; ni++)
        bfr[ni] = *(const bf16x8*)&lB[(wc * 64 + ni * 16 + lc) * 64 + (((kk * 4 + lr) ^ sw) * 8)];
#pragma unroll
      for (int mi = 0; mi < 4; mi++)
#pragma unroll
        for (int ni = 0; ni < 4; ni++)
          acc[mi][ni] = MFMA32(afr[mi], bfr[ni], acc[mi][ni], 0, 0, 0);
    }
  };

  for (int t = 0; t < 6; ++t) {
    stage(t);
    __syncthreads();
    compute();
    if (t < 5) __syncthreads();
  }

  float bo[4];
#pragma unroll
  for (int ni = 0; ni < 4; ni++) bo[ni] = bout[n0 + wc * 64 + ni * 16 + lc];

#pragma unroll
  for (int mi = 0; mi < 4; mi++) {
    int row = m0 + wr * 64 + mi * 16 + lr * 4;
#pragma unroll
    for (int reg = 0; reg < 4; reg++) {
      size_t rb = (size_t)(row + reg) * DIM + n0 + wc * 64 + lc;
#pragma unroll
      for (int ni = 0; ni < 4; ni++)
        out[rb + ni * 16] = acc[mi][ni][reg] + bo[ni];
    }
  }
}

// ---------------------------------------------------------------- launch
extern "C" void kernel_launch(void* const* d_in, const int* in_sizes, int n_in,
                              void* d_out, int out_size, void* d_ws, size_t ws_size,
                              hipStream_t stream) {
  const float* x    = (const float*)d_in[0];
  const float* wqkv = (const float*)d_in[1];
  const float* pos  = (const float*)d_in[2];
  const float* wout = (const float*)d_in[3];
  const float* bout = (const float*)d_in[4];
  float* out = (float*)d_out;

  char* ws = (char*)d_ws;
  unsigned short* wqkvT = (unsigned short*)ws;                          // 1152*384*2 = 884736
  unsigned short* woutT = (unsigned short*)(ws + 884736);               // 384*384*2  = 294912
  unsigned short* qkv   = (unsigned short*)(ws + 1179648);              // 65536*1152*2 = 150994944
  unsigned short* xb    = (unsigned short*)(ws + 1179648 + 150994944);  // 65536*384*2  = 50331648
  unsigned short* Zb    = xb;        // xb dead after gemm_qkv; attn reuses region
  float* tab = out;                  // d_out as scratch for 64KB bias table

  convert_all<<<14080, 256, 0, stream>>>(x, wqkv, wout, pos, xb, wqkvT, woutT, tab);
  gemm_qkv<<<2304, 256, 0, stream>>>(xb, wqkvT, qkv);
  attn_kernel<<<3072, 256, 0, stream>>>(qkv, tab, Zb);
  gemm_out<<<1536, 256, 0, stream>>>(Zb, woutT, bout, out);
}

// Round 11
// 178.861 us; speedup vs baseline: 1.8645x; 1.0329x over previous
//
#include <hip/hip_runtime.h>
#include <stdint.h>

#define HEADS 12
#define HD 32
#define DIM 384
#define NQKV 1152
#define NPIX 4096
#define NB 16

typedef __attribute__((ext_vector_type(8))) short bf16x8;
typedef __attribute__((ext_vector_type(4))) float f32x4;

__device__ __forceinline__ unsigned short f2bf(float f) {
  uint32_t u = __builtin_bit_cast(uint32_t, f);
  u += 0x7FFF + ((u >> 16) & 1);
  return (unsigned short)(u >> 16);
}

__device__ __forceinline__ uint32_t cvtpk(float lo, float hi) {
  uint32_t r;
  asm("v_cvt_pk_bf16_f32 %0, %1, %2" : "=v"(r) : "v"(lo), "v"(hi));
  return r;
}

#define GL_LDS(gp, lp) __builtin_amdgcn_global_load_lds( \
    (const __attribute__((address_space(1))) void*)(gp),  \
    (__attribute__((address_space(3))) void*)(lp), 16, 0, 0)

#define MFMA32 __builtin_amdgcn_mfma_f32_16x16x32_bf16

// ---------------------------------------------------------------- converts
// blocks [0,12288): x f32 -> bf16; [12288,14016): weight transposes;
// [14016,14080): bias+mask table [4][64][64] f32 (written to d_out scratch).
__global__ void convert_all(const float* __restrict__ x,
                            const float* __restrict__ wqkv,
                            const float* __restrict__ wout,
                            const float* __restrict__ pos,
                            unsigned short* __restrict__ xb,
                            unsigned short* __restrict__ wqkvT,
                            unsigned short* __restrict__ woutT,
                            float* __restrict__ tab) {
  int bid = blockIdx.x;
  if (bid < 12288) {
    int i = bid * 256 + threadIdx.x;          // 3145728 threads x 8 elems
    const float4* xp = (const float4*)x;
    float4 a = xp[2 * i], b2 = xp[2 * i + 1];
    union { bf16x8 v; unsigned short s[8]; } u;
    u.s[0] = f2bf(a.x);  u.s[1] = f2bf(a.y);
    u.s[2] = f2bf(a.z);  u.s[3] = f2bf(a.w);
    u.s[4] = f2bf(b2.x); u.s[5] = f2bf(b2.y);
    u.s[6] = f2bf(b2.z); u.s[7] = f2bf(b2.w);
    ((bf16x8*)xb)[i] = u.v;
  } else if (bid < 14016) {
    int tid = (bid - 12288) * 256 + threadIdx.x;
    if (tid < NQKV * DIM) {                   // wqkvT[n][k] = wqkv[k][n]
      int n = tid / DIM, k = tid % DIM;
      wqkvT[tid] = f2bf(wqkv[(size_t)k * NQKV + n]);
    }
    if (tid < DIM * DIM) {                    // woutT[n][k] = wout[k][n]
      int n = tid / DIM, k = tid % DIM;
      woutT[tid] = f2bf(wout[(size_t)k * DIM + n]);
    }
  } else {
    int tid = (bid - 14016) * 256 + threadIdx.x;  // 0..16383
    int v = tid >> 12, rem = tid & 4095;
    int i = rem >> 6, j = rem & 63;
    int xi = i >> 3, yi = i & 7, xj = j >> 3, yj = j & 7;
    float val = pos[(xj - xi + 7) * 15 + (yj - yi + 7)];
    if ((v & 1) && ((i >= 32) != (j >= 32))) val = -1e30f;
    if ((v & 2) && ((yi >= 4) != (yj >= 4))) val = -1e30f;
    tab[tid] = val;
  }
}

// ---------------------------------------------------------------- GEMM1: qkv = xb @ wqkvT^T
// R4-exact m97 structure: single-buffer 32KB LDS, 2 barriers/K-step, 16B
// global_load_lds, XOR-swizzled LDS via pre-swizzled global source col,
// XCD-chunked block remap. (BM=256 refuted R10: 74 vs 67 us.)
__global__ __launch_bounds__(256, 4) void gemm_qkv(
    const unsigned short* __restrict__ xb,   // [65536][384]
    const unsigned short* __restrict__ wT,   // [1152][384]
    unsigned short* __restrict__ qkv)        // [65536][1152]
{
  __shared__ unsigned short lA[128 * 64];
  __shared__ unsigned short lB[128 * 64];
  const int tid = threadIdx.x;
  const int wid = tid >> 6, lane = tid & 63;
  const int wr = wid >> 1, wc = wid & 1;
  const int lr = lane >> 4, lc = lane & 15;

  // XCD swizzle: 4608 blocks = 8 xcd * (64 mt * 9 nt)
  const int f = blockIdx.x;
  const int xcd = f & 7, idx = f >> 3;
  const int nt = idx % 9, mt = xcd * 64 + idx / 9;
  const int m0 = mt * 128, n0 = nt * 128;

  const int srow = wid * 32 + (lane >> 3);                 // + i*8 per inst
  const int scol = ((lane & 7) ^ (lane >> 3)) * 8;         // pre-swizzled src col
  const unsigned short* agp = xb + (size_t)(m0 + srow) * DIM + scol;
  const unsigned short* bgp = wT + (size_t)(n0 + srow) * DIM + scol;

  const f32x4 z4 = {0.f, 0.f, 0.f, 0.f};
  f32x4 acc[4][4];
#pragma unroll
  for (int i = 0; i < 4; i++)
#pragma unroll
    for (int j = 0; j < 4; j++) acc[i][j] = z4;

  auto stage = [&](int t) {
#pragma unroll
    for (int i = 0; i < 4; i++) {
      GL_LDS(agp + (size_t)(i * 8) * DIM + t * 64, &lA[(wid * 4 + i) * 512]);
      GL_LDS(bgp + (size_t)(i * 8) * DIM + t * 64, &lB[(wid * 4 + i) * 512]);
    }
  };
  auto compute = [&]() {
    const int sw = lc & 7;
#pragma unroll
    for (int kk = 0; kk < 2; kk++) {
      bf16x8 afr[4], bfr[4];
#pragma unroll
      for (int mi = 0; mi < 4; mi++)
        afr[mi] = *(const bf16x8*)&lA[(wr * 64 + mi * 16 + lc) * 64 + (((kk * 4 + lr) ^ sw) * 8)];
#pragma unroll
      for (int ni = 0; ni < 4; ni++)
        bfr[ni] = *(const bf16x8*)&lB[(wc * 64 + ni * 16 + lc) * 64 + (((kk * 4 + lr) ^ sw) * 8)];
#pragma unroll
      for (int mi = 0; mi < 4; mi++)
#pragma unroll
        for (int ni = 0; ni < 4; ni++)
          acc[mi][ni] = MFMA32(afr[mi], bfr[ni], acc[mi][ni], 0, 0, 0);
    }
  };

  for (int t = 0; t < 6; ++t) {
    stage(t);
    __syncthreads();
    compute();
    if (t < 5) __syncthreads();
  }

#pragma unroll
  for (int mi = 0; mi < 4; mi++) {
    int row = m0 + wr * 64 + mi * 16 + lr * 4;
#pragma unroll
    for (int reg = 0; reg < 4; reg++) {
      size_t rb = (size_t)(row + reg) * NQKV + n0 + wc * 64 + lc;
#pragma unroll
      for (int ni = 0; ni < 4; ni++)
        qkv[rb + ni * 16] = f2bf(acc[mi][ni][reg]);
    }
  }
}

// ---------------------------------------------------------------- attention (R4 verbatim)
// one wave per (b, head, window); swapped QK^T (S^T in regs), in-register
// softmax + normalize, cvt_pk+ds_bpermute P redistribution (no P LDS),
// XOR-swizzled wave-private V^T LDS, no __syncthreads.
__global__ __launch_bounds__(256) void attn_kernel(
    const unsigned short* __restrict__ qkv,  // [65536][1152] bf16
    const float* __restrict__ tab,           // [4][64][64] bias+mask
    unsigned short* __restrict__ Z)          // [65536][384] bf16
{
  __shared__ unsigned short Vt[4][32 * 80];

  const int wid = threadIdx.x >> 6, lane = threadIdx.x & 63;
  const int lr = lane >> 4, lc = lane & 15;
  const int task = blockIdx.x * 4 + wid;          // 12288 tasks
  const int win = task & 63;
  const int head = (task >> 6) % HEADS;
  const int b = task / (HEADS * 64);
  const int wh = win >> 3, ww = win & 7;
  const float* tv = tab + (((wh == 7) ? 1 : 0) + ((ww == 7) ? 2 : 0)) * 4096;

  auto pixof = [&](int t) {
    int hh = (wh * 8 + (t >> 3) + 4) & 63;
    int w2 = (ww * 8 + (t & 7) + 4) & 63;
    return hh * 64 + w2;
  };

  unsigned short* vt = &Vt[wid][0];
  bf16x8 qf[4], kf[4];
#pragma unroll
  for (int g = 0; g < 4; ++g) {
    int t = g * 16 + lc;
    const unsigned short* base =
        qkv + (size_t)(b * NPIX + pixof(t)) * NQKV + head * HD + lr * 8;
    qf[g] = *(const bf16x8*)(base);
    kf[g] = *(const bf16x8*)(base + DIM);
    union { bf16x8 v; unsigned short s[8]; } uv;
    uv.v = *(const bf16x8*)(base + 2 * DIM);
    // Vt[d][t] = V[t][d], col-block XOR-swizzled by (d>>2)&3
#pragma unroll
    for (int j = 0; j < 8; j++) {
      int row = lr * 8 + j;
      int addr = row * 80 + (((g * 2 + (lc >> 3)) ^ ((row >> 2) & 3)) << 3) + (lc & 7);
      vt[addr] = uv.s[j];
    }
  }

  const float SC = 0.17677669529663687f;   // 32^-0.5
  const f32x4 z4 = {0.f, 0.f, 0.f, 0.f};
  uint32_t pf[4][2][4];                    // [i-tile][kslot][u32 pair]
  const int srcA = (lc + 16 * (2 * (lr & 1))) << 2;   // lane byte-addr, lr'=2(lr&1)
  const int srcB = srcA + 64;                         // lr'=2(lr&1)+1
  const bool hiSel = (lr >> 1) != 0;

#pragma unroll
  for (int bq = 0; bq < 4; bq++) {
    // bias tile: T[i = bq*16+lc][j = 16a+4lr+reg], contiguous 4 j's
    f32x4 tb[4];
#pragma unroll
    for (int a = 0; a < 4; a++)
      tb[a] = *(const f32x4*)&tv[(bq * 16 + lc) * 64 + a * 16 + lr * 4];
    // swapped QK^T: s[a][reg] = S^T[j = 16a+4lr+reg][i = bq*16+lc]
    f32x4 s[4];
#pragma unroll
    for (int a = 0; a < 4; a++)
      s[a] = MFMA32(kf[a], qf[bq], z4, 0, 0, 0);

    float m = -3.0e38f;
#pragma unroll
    for (int a = 0; a < 4; a++)
#pragma unroll
      for (int r = 0; r < 4; r++) {
        float val = s[a][r] * SC + tb[a][r];
        s[a][r] = val;
        m = fmaxf(m, val);
      }
    m = fmaxf(m, __shfl_xor(m, 16));
    m = fmaxf(m, __shfl_xor(m, 32));
    float sum = 0.f;
#pragma unroll
    for (int a = 0; a < 4; a++)
#pragma unroll
      for (int r = 0; r < 4; r++) {
        float p = exp2f((s[a][r] - m) * 1.44269504f);
        s[a][r] = p;
        sum += p;
      }
    sum += __shfl_xor(sum, 16);
    sum += __shfl_xor(sum, 32);
    float iv = 1.0f / sum;

    // pack normalized P to bf16 pairs: pk[a][w] = (reg 2w, reg 2w+1)
    uint32_t pk[4][2];
#pragma unroll
    for (int a = 0; a < 4; a++)
#pragma unroll
      for (int w = 0; w < 2; w++)
        pk[a][w] = cvtpk(s[a][2 * w] * iv, s[a][2 * w + 1] * iv);
    // redistribute: pf[bq][kk] elem-pair wp holds j = 32kk+8lr+2wp,+1
    // source: lane lr' = 2(lr&1)+(wp>>1), slot pk[2kk + (lr>>1)][wp&1]
#pragma unroll
    for (int kk = 0; kk < 2; kk++)
#pragma unroll
      for (int wp = 0; wp < 4; wp++) {
        int sa = (wp >> 1) ? srcB : srcA;
        uint32_t lo = (uint32_t)__builtin_amdgcn_ds_bpermute(sa, (int)pk[2 * kk][wp & 1]);
        uint32_t hi = (uint32_t)__builtin_amdgcn_ds_bpermute(sa, (int)pk[2 * kk + 1][wp & 1]);
        pf[bq][kk][wp] = hiSel ? hi : lo;
      }
  }

  asm volatile("s_waitcnt lgkmcnt(0)" ::: "memory");

  f32x4 oacc[4][2];
#pragma unroll
  for (int i = 0; i < 4; i++) { oacc[i][0] = z4; oacc[i][1] = z4; }

#pragma unroll
  for (int kk = 0; kk < 2; kk++) {
    bf16x8 vfr[2];
#pragma unroll
    for (int dt = 0; dt < 2; dt++) {
      int rowd = dt * 16 + lc;
      int addr = rowd * 80 + ((((kk * 4 + lr) ^ (lc >> 2)) & 7) << 3);
      vfr[dt] = *(const bf16x8*)&vt[addr];
    }
#pragma unroll
    for (int mi = 0; mi < 4; mi++) {
      union { uint32_t u[4]; bf16x8 v; } pu;
      pu.u[0] = pf[mi][kk][0]; pu.u[1] = pf[mi][kk][1];
      pu.u[2] = pf[mi][kk][2]; pu.u[3] = pf[mi][kk][3];
#pragma unroll
      for (int dt = 0; dt < 2; dt++)
        oacc[mi][dt] = MFMA32(pu.v, vfr[dt], oacc[mi][dt], 0, 0, 0);
    }
  }

#pragma unroll
  for (int mi = 0; mi < 4; mi++) {
#pragma unroll
    for (int reg = 0; reg < 4; reg++) {
      int i = mi * 16 + lr * 4 + reg;
      size_t zb = ((size_t)b * NPIX + pixof(i)) * DIM + head * HD;
#pragma unroll
      for (int dt = 0; dt < 2; dt++)
        Z[zb + dt * 16 + lc] = f2bf(oacc[mi][dt][reg]);
    }
  }
}

// ---------------------------------------------------------------- GEMM2: out = Z @ woutT^T + b
// m97 single-buffer structure + XCD swizzle. M=65536, N=384, K=384.
__global__ __launch_bounds__(256, 4) void gemm_out(
    const unsigned short* __restrict__ Zb,   // [65536][384]
    const unsigned short* __restrict__ wT,   // [384][384]
    const float* __restrict__ bout,
    float* __restrict__ out)                 // [65536][384]
{
  __shared__ unsigned short lA[128 * 64];
  __shared__ unsigned short lB[128 * 64];
  const int tid = threadIdx.x;
  const int wid = tid >> 6, lane = tid & 63;
  const int wr = wid >> 1, wc = wid & 1;
  const int lr = lane >> 4, lc = lane & 15;

  // XCD swizzle: 1536 blocks = 8 xcd * (64 mt * 3 nt)
  const int f = blockIdx.x;
  const int xcd = f & 7, idx = f >> 3;
  const int nt = idx % 3, mt = xcd * 64 + idx / 3;
  const int m0 = mt * 128, n0 = nt * 128;

  const int srow = wid * 32 + (lane >> 3);
  const int scol = ((lane & 7) ^ (lane >> 3)) * 8;
  const unsigned short* agp = Zb + (size_t)(m0 + srow) * DIM + scol;
  const unsigned short* bgp = wT + (size_t)(n0 + srow) * DIM + scol;

  const f32x4 z4 = {0.f, 0.f, 0.f, 0.f};
  f32x4 acc[4][4];
#pragma unroll
  for (int i = 0; i < 4; i++)
#pragma unroll
    for (int j = 0; j < 4; j++) acc[i][j] = z4;

  auto stage = [&](int t) {
#pragma unroll
    for (int i = 0; i < 4; i++) {
      GL_LDS(agp + (size_t)(i * 8) * DIM + t * 64, &lA[(wid * 4 + i) * 512]);
      GL_LDS(bgp + (size_t)(i * 8) * DIM + t * 64, &lB[(wid * 4 + i) * 512]);
    }
  };
  auto compute = [&]() {
    const int sw = lc & 7;
#pragma unroll
    for (int kk = 0; kk < 2; kk++) {
      bf16x8 afr[4], bfr[4];
#pragma unroll
      for (int mi = 0; mi < 4; mi++)
        afr[mi] = *(const bf16x8*)&lA[(wr * 64 + mi * 16 + lc) * 64 + (((kk * 4 + lr) ^ sw) * 8)];
#pragma unroll
      for (int ni = 0; ni < 4; ni++)
        bfr[ni] = *(const bf16x8*)&lB[(wc * 64 + ni * 16 + lc) * 64 + (((kk * 4 + lr) ^ sw) * 8)];
#pragma unroll
      for (int mi = 0; mi < 4; mi++)
#pragma unroll
        for (int ni = 0; ni < 4; ni++)
          acc[mi][ni] = MFMA32(afr[mi], bfr[ni], acc[mi][ni], 0, 0, 0);
    }
  };

  for (int t = 0; t < 6; ++t) {
    stage(t);
    __syncthreads();
    compute();
    if (t < 5) __syncthreads();
  }

  float bo[4];
#pragma unroll
  for (int ni = 0; ni < 4; ni++) bo[ni] = bout[n0 + wc * 64 + ni * 16 + lc];

#pragma unroll
  for (int mi = 0; mi < 4; mi++) {
    int row = m0 + wr * 64 + mi * 16 + lr * 4;
#pragma unroll
    for (int reg = 0; reg < 4; reg++) {
      size_t rb = (size_t)(row + reg) * DIM + n0 + wc * 64 + lc;
#pragma unroll
      for (int ni = 0; ni < 4; ni++)
        out[rb + ni * 16] = acc[mi][ni][reg] + bo[ni];
    }
  }
}

// ---------------------------------------------------------------- launch
extern "C" void kernel_launch(void* const* d_in, const int* in_sizes, int n_in,
                              void* d_out, int out_size, void* d_ws, size_t ws_size,
                              hipStream_t stream) {
  const float* x    = (const float*)d_in[0];
  const float* wqkv = (const float*)d_in[1];
  const float* pos  = (const float*)d_in[2];
  const float* wout = (const float*)d_in[3];
  const float* bout = (const float*)d_in[4];
  float* out = (float*)d_out;

  char* ws = (char*)d_ws;
  unsigned short* wqkvT = (unsigned short*)ws;                          // 1152*384*2 = 884736
  unsigned short* woutT = (unsigned short*)(ws + 884736);               // 384*384*2  = 294912
  unsigned short* qkv   = (unsigned short*)(ws + 1179648);              // 65536*1152*2 = 150994944
  unsigned short* xb    = (unsigned short*)(ws + 1179648 + 150994944);  // 65536*384*2  = 50331648
  unsigned short* Zb    = xb;        // xb dead after gemm_qkv; attn reuses region
  float* tab = out;                  // d_out as scratch for 64KB bias table

  convert_all<<<14080, 256, 0, stream>>>(x, wqkv, wout, pos, xb, wqkvT, woutT, tab);
  gemm_qkv<<<4608, 256, 0, stream>>>(xb, wqkvT, qkv);
  attn_kernel<<<3072, 256, 0, stream>>>(qkv, tab, Zb);
  gemm_out<<<1536, 256, 0, stream>>>(Zb, woutT, bout, out);
}